// Round 3
// baseline (831.256 us; speedup 1.0000x reference)
//
#include <hip/hip_runtime.h>
#include <hip/hip_bf16.h>

// Attention fwd: B=4 H=16 S=2048 D=128, fp32 in/out, scale = 128^-0.5.
// Prep (one fused kernel): V -> VT[bh][d][s] bf16 and K -> Kb[bh][s][d] bf16
// in d_ws (64 MB). fattn: 256 thr = 4 waves, 64 Q-rows/block, KV tiles of 64.
// T14 async staging: next tile's K/V global loads issue BEFORE compute of the
// current tile (32 VGPRs in flight), ds_writes land after the post-compute
// barrier -> L2 latency hidden under QK+softmax+PV.
// Q held in registers (pre-scaled by scale*log2e). Defer-max softmax:
// fast path has NO cross-lane reductions (local max + __any ballot only);
// l is accumulated as per-lane partials, reduced once in the epilogue.
// P written as packed b32 pairs (shfl_xor(1) + cvt_pk) -> bank-conflict free.
// LDS = 45,056 B -> 3 blocks/CU.

#define SEQ 2048
#define DH  128
#define NBH 64          // B*H
#define BM  64          // Q rows per block
#define BN  64          // keys per KV iteration
#define NT  (SEQ / BN)  // 32 KV tiles
#define QK_LD 136       // bf16 elems per row for K tile (128+8): 272B rows
#define VT_LD 72        // (64+8): 144B rows
#define P_LD  72
#define THR 8.0f        // defer-max threshold (exp2 domain): P <= 2^8

typedef __attribute__((ext_vector_type(8))) short short8;
typedef __attribute__((ext_vector_type(4))) float f32x4;

#if __has_builtin(__builtin_amdgcn_exp2f)
#define EXP2F(x) __builtin_amdgcn_exp2f(x)
#else
#define EXP2F(x) exp2f(x)
#endif

// softmax scale folded with log2(e), pre-applied to Q at load time
#define CS (0.08838834764831845f * 1.44269504088896340736f)

__device__ __forceinline__ unsigned int pk_bf16(float lo, float hi) {
    union { __hip_bfloat162 h; unsigned int u; } cv;
    cv.h = __float22bfloat162_rn(make_float2(lo, hi));   // v_cvt_pk_bf16_f32
    return cv.u;
}

// ---- fused prep: V[bh][s][d] f32 -> VT[bh][d][s] bf16 (transpose) and,
// ---- if DOK, K f32 -> bf16 streaming convert (same layout). ----
template<bool DOK>
__global__ __launch_bounds__(256) void prep_kernel(
        const float* __restrict__ v, unsigned short* __restrict__ vt,
        const float* __restrict__ k, unsigned short* __restrict__ kb) {
    __shared__ float tile[64][65];          // +1 pad: transposed reads 2-way free
    const int bh = blockIdx.z;
    const int s0 = blockIdx.x * 64;
    const int d0 = blockIdx.y * 64;
    const int tid = threadIdx.x;

    // --- K convert slice: block-linear id owns 4096 consecutive floats ---
    if (DOK) {
        const size_t kbase = ((size_t)blockIdx.x +
                              32 * ((size_t)blockIdx.y + 2 * (size_t)blockIdx.z)) * 4096;
#pragma unroll
        for (int i = 0; i < 4; ++i) {
            size_t idx = kbase + ((size_t)tid + 256 * i) * 4;
            float4 val = *reinterpret_cast<const float4*>(k + idx);
            uint2 pk;
            pk.x = pk_bf16(val.x, val.y);
            pk.y = pk_bf16(val.z, val.w);
            *reinterpret_cast<uint2*>(kb + idx) = pk;
        }
    }

    // --- V transpose ---
    const float* src = v + ((size_t)bh * SEQ + s0) * DH + d0;
#pragma unroll
    for (int i = 0; i < 4; ++i) {
        int id  = tid + 256 * i;
        int row = id >> 4;                  // 0..63 key
        int c4  = (id & 15) << 2;           // 0..60 d offset
        float4 val = *reinterpret_cast<const float4*>(src + row * DH + c4);
        tile[row][c4 + 0] = val.x;
        tile[row][c4 + 1] = val.y;
        tile[row][c4 + 2] = val.z;
        tile[row][c4 + 3] = val.w;
    }
    __syncthreads();
    unsigned short* dst = vt + ((size_t)bh * DH + d0) * SEQ + s0;
#pragma unroll
    for (int i = 0; i < 2; ++i) {
        int id = tid + 256 * i;
        int dd = id >> 3;                   // 0..63 d row
        int kc = (id & 7) << 3;             // key chunk of 8
        uint4 pk;
        unsigned int* pw = reinterpret_cast<unsigned int*>(&pk);
#pragma unroll
        for (int j = 0; j < 4; ++j)
            pw[j] = pk_bf16(tile[kc + 2 * j][dd], tile[kc + 2 * j + 1][dd]);
        *reinterpret_cast<uint4*>(dst + (size_t)dd * SEQ + kc) = pk;   // 16B coalesced
    }
}

// ---- flash attention ----
template<bool KPRE>
__global__ __launch_bounds__(256, 3) void fattn_kernel(
        const float* __restrict__ q, const float* __restrict__ kf,
        const unsigned short* __restrict__ kb,
        const unsigned short* __restrict__ vt, float* __restrict__ out) {
    __shared__ unsigned short Ks[BN * QK_LD];   // [key][d]
    __shared__ unsigned short Vs[DH * VT_LD];   // [d][key]  (transposed V tile)
    __shared__ unsigned short Ps[BM * P_LD];    // [q_row][key]

    // XCD swizzle: cluster the 32 q-blocks of each bh on one XCD (2048 = 8*256)
    const int wid = ((blockIdx.x & 7) << 8) | (blockIdx.x >> 3);
    const int bh  = wid >> 5;
    const int q0  = (wid & 31) * BM;
    const int tid  = threadIdx.x;
    const int w    = tid >> 6;      // wave 0..3
    const int lane = tid & 63;
    const int l15  = lane & 15;
    const int quad = lane >> 4;

    // ---- Q (16 rows for this wave) into registers, scaled by CS, bf16 ----
    short8 qf[4];
    {
        const float* qptr = q + ((size_t)bh * SEQ + q0 + w * 16 + l15) * DH + quad * 8;
#pragma unroll
        for (int kk = 0; kk < 4; ++kk) {
            float4 x = *reinterpret_cast<const float4*>(qptr + kk * 32);
            float4 y = *reinterpret_cast<const float4*>(qptr + kk * 32 + 4);
            union { short8 s; uint4 u; } cv;
            cv.u.x = pk_bf16(x.x * CS, x.y * CS);
            cv.u.y = pk_bf16(x.z * CS, x.w * CS);
            cv.u.z = pk_bf16(y.x * CS, y.y * CS);
            cv.u.w = pk_bf16(y.z * CS, y.w * CS);
            qf[kk] = cv.s;
        }
    }

    f32x4 o[8];
#pragma unroll
    for (int t = 0; t < 8; ++t) o[t] = (f32x4){0.f, 0.f, 0.f, 0.f};
    float mrow[4] = {-1e30f, -1e30f, -1e30f, -1e30f};
    float lrow[4] = {0.f, 0.f, 0.f, 0.f};   // per-lane PARTIAL sums (reduced in epilogue)

    const float*          kfp  = kf + (size_t)bh * SEQ * DH;
    const unsigned short* kbp  = kb + (size_t)bh * SEQ * DH;
    const unsigned short* vptr = vt + (size_t)bh * DH * SEQ;

    unsigned int* Ps32 = reinterpret_cast<unsigned int*>(Ps);
    const int prow_base = w * 16 + quad * 4;
    // within-row dword offset for packed P writes: evens own t0/t2, odds t1/t3
    const int pdw = (l15 & 1) ? (8 + (l15 >> 1)) : (l15 >> 1);

    // ---- T14 async staging state (KPRE path): next tile in registers ----
    uint4 kreg[4], vreg[4];
    const int krow = tid >> 4, kcol = (tid & 15) << 3;   // K stage coords
    const int vrow = tid >> 3, vcol = (tid & 7) << 3;    // V stage coords

#define LOAD_TILE(KT)                                                          \
    do {                                                                       \
        const int _k0 = (KT) * BN;                                             \
        _Pragma("unroll")                                                      \
        for (int i = 0; i < 4; ++i)                                            \
            kreg[i] = *reinterpret_cast<const uint4*>(                         \
                kbp + (size_t)(_k0 + krow + 16 * i) * DH + kcol);              \
        _Pragma("unroll")                                                      \
        for (int i = 0; i < 4; ++i)                                            \
            vreg[i] = *reinterpret_cast<const uint4*>(                         \
                vptr + (size_t)(vrow + 32 * i) * SEQ + _k0 + vcol);            \
    } while (0)

#define WRITE_TILE()                                                           \
    do {                                                                       \
        _Pragma("unroll")                                                      \
        for (int i = 0; i < 4; ++i)                                            \
            *reinterpret_cast<uint4*>(&Ks[(krow + 16 * i) * QK_LD + kcol]) = kreg[i]; \
        _Pragma("unroll")                                                      \
        for (int i = 0; i < 4; ++i)                                            \
            *reinterpret_cast<uint4*>(&Vs[(vrow + 32 * i) * VT_LD + vcol]) = vreg[i]; \
    } while (0)

    if (KPRE) {
        LOAD_TILE(0);
        WRITE_TILE();
        __syncthreads();
    }

    for (int kt = 0; kt < NT; ++kt) {
        const int k0 = kt * BN;
        if (KPRE) {
            // issue next tile's global loads now; latency hides under compute
            if (kt + 1 < NT) LOAD_TILE(kt + 1);
        } else {
            // fallback (small ws): synchronous stage, f32 K -> bf16 via cvt_pk
#pragma unroll
            for (int i = 0; i < 8; ++i) {
                int id  = tid + 256 * i;
                int row = id >> 5;
                int c4  = (id & 31) << 2;
                float4 val = *reinterpret_cast<const float4*>(kfp + (size_t)(k0 + row) * DH + c4);
                uint2 pk;
                pk.x = pk_bf16(val.x, val.y);
                pk.y = pk_bf16(val.z, val.w);
                *reinterpret_cast<uint2*>(&Ks[row * QK_LD + c4]) = pk;
            }
#pragma unroll
            for (int i = 0; i < 4; ++i) {
                int id = tid + 256 * i;
                int dd = id >> 3;
                int kc = (id & 7) << 3;
                *reinterpret_cast<uint4*>(&Vs[dd * VT_LD + kc]) =
                    *reinterpret_cast<const uint4*>(vptr + (size_t)dd * SEQ + k0 + kc);
            }
            __syncthreads();
        }

        // ---- S = Q K^T (pre-scaled): wave w computes rows [w*16,w*16+16) x 64 keys
        f32x4 acc[4];
#pragma unroll
        for (int t = 0; t < 4; ++t) acc[t] = (f32x4){0.f, 0.f, 0.f, 0.f};
#pragma unroll
        for (int kk = 0; kk < 4; ++kk) {
            const int koff = kk * 32 + quad * 8;
#pragma unroll
            for (int t = 0; t < 4; ++t) {
                short8 b = *reinterpret_cast<const short8*>(&Ks[(t * 16 + l15) * QK_LD + koff]);
                acc[t] = __builtin_amdgcn_mfma_f32_16x16x32_bf16(qf[kk], b, acc[t], 0, 0, 0);
            }
        }

        // ---- defer-max: fast path needs no cross-lane reduction at all ----
        float lm[4];
#pragma unroll
        for (int r = 0; r < 4; ++r)
            lm[r] = fmaxf(fmaxf(acc[0][r], acc[1][r]), fmaxf(acc[2][r], acc[3][r]));
        float need = fmaxf(fmaxf(lm[0] - mrow[0], lm[1] - mrow[1]),
                           fmaxf(lm[2] - mrow[2], lm[3] - mrow[3]));
        if (__any(need > THR)) {
            // slow path (first tile + rare growth): full row max, rescale o/l
#pragma unroll
            for (int r = 0; r < 4; ++r) {
                float mx = lm[r];
#pragma unroll
                for (int off = 1; off < 16; off <<= 1)
                    mx = fmaxf(mx, __shfl_xor(mx, off));
                float mnew  = fmaxf(mrow[r], mx);
                float alpha = EXP2F(mrow[r] - mnew);
                mrow[r] = mnew;
                lrow[r] *= alpha;
#pragma unroll
                for (int t = 0; t < 8; ++t) o[t][r] *= alpha;
            }
        }

        // ---- P = exp2(S - m) (bounded by 2^8), packed conflict-free writes ----
#pragma unroll
        for (int r = 0; r < 4; ++r) {
            float p0 = EXP2F(acc[0][r] - mrow[r]);
            float p1 = EXP2F(acc[1][r] - mrow[r]);
            float p2 = EXP2F(acc[2][r] - mrow[r]);
            float p3 = EXP2F(acc[3][r] - mrow[r]);
            lrow[r] += (p0 + p1) + (p2 + p3);
            unsigned int a01 = pk_bf16(p0, p1);
            unsigned int a23 = pk_bf16(p2, p3);
            unsigned int s01 = __shfl_xor((int)a01, 1);
            unsigned int s23 = __shfl_xor((int)a23, 1);
            unsigned int w0, w1;
            if (l15 & 1) {  // odd lanes own t1/t3 dwords: low = partner's, high = own
                w0 = (s01 >> 16) | (a01 & 0xffff0000u);
                w1 = (s23 >> 16) | (a23 & 0xffff0000u);
            } else {        // even lanes own t0/t2 dwords: low = own, high = partner's
                w0 = (a01 & 0xffffu) | (s01 << 16);
                w1 = (a23 & 0xffffu) | (s23 << 16);
            }
            const int dw = (prow_base + r) * (P_LD / 2) + pdw;
            Ps32[dw]      = w0;   // cols {t0|t1}
            Ps32[dw + 16] = w1;   // cols {t2|t3}
        }

        // ---- O += P V : A-frag from own P rows, B-frag from VT tile ----
#pragma unroll
        for (int kk = 0; kk < 2; ++kk) {
            const int koff = kk * 32 + quad * 8;
            short8 a = *reinterpret_cast<const short8*>(&Ps[(w * 16 + l15) * P_LD + koff]);
#pragma unroll
            for (int t = 0; t < 8; ++t) {
                short8 b = *reinterpret_cast<const short8*>(&Vs[(t * 16 + l15) * VT_LD + koff]);
                o[t] = __builtin_amdgcn_mfma_f32_16x16x32_bf16(a, b, o[t], 0, 0, 0);
            }
        }
        __syncthreads();   // all waves done reading K/V tiles
        if (KPRE) {
            if (kt + 1 < NT) WRITE_TILE();   // vmcnt drained here, not pre-compute
            __syncthreads();                 // LDS ready for next compute
        }
    }

    // ---- epilogue: reduce distributed l, normalize, store fp32 ----
#pragma unroll
    for (int r = 0; r < 4; ++r) {
#pragma unroll
        for (int off = 1; off < 16; off <<= 1)
            lrow[r] += __shfl_xor(lrow[r], off);
    }
    float* obase = out + ((size_t)bh * SEQ + q0) * DH;
#pragma unroll
    for (int r = 0; r < 4; ++r) {
        float inv = 1.0f / lrow[r];
        int row = w * 16 + quad * 4 + r;
#pragma unroll
        for (int t = 0; t < 8; ++t)
            obase[(size_t)row * DH + t * 16 + l15] = o[t][r] * inv;
    }
}

extern "C" void kernel_launch(void* const* d_in, const int* in_sizes, int n_in,
                              void* d_out, int out_size, void* d_ws, size_t ws_size,
                              hipStream_t stream) {
    const float* q = (const float*)d_in[0];
    const float* k = (const float*)d_in[1];
    const float* v = (const float*)d_in[2];
    float* out = (float*)d_out;
    unsigned short* vt = (unsigned short*)d_ws;                   // 32 MB

    const size_t vt_elems = (size_t)NBH * SEQ * DH;               // 16M shorts
    if (ws_size >= 2 * vt_elems * sizeof(unsigned short)) {
        unsigned short* kbuf = vt + vt_elems;
        prep_kernel<true><<<dim3(SEQ / 64, DH / 64, NBH), dim3(256), 0, stream>>>(v, vt, k, kbuf);
        fattn_kernel<true><<<dim3(SEQ / BM * NBH), dim3(256), 0, stream>>>(q, nullptr, kbuf, vt, out);
    } else {
        prep_kernel<false><<<dim3(SEQ / 64, DH / 64, NBH), dim3(256), 0, stream>>>(v, vt, nullptr, nullptr);
        fattn_kernel<false><<<dim3(SEQ / BM * NBH), dim3(256), 0, stream>>>(q, k, nullptr, vt, out);
    }
}

// Round 4
// 419.904 us; speedup vs baseline: 1.9796x; 1.9796x over previous
//
#include <hip/hip_runtime.h>
#include <hip/hip_bf16.h>

// Attention fwd: B=4 H=16 S=2048 D=128, fp32 in/out, scale = 128^-0.5.
// Prep (one fused kernel): V -> VT[bh][d][s] bf16 and K -> Kb[bh][s][d] bf16
// in d_ws (64 MB). fattn: 256 thr = 4 waves, 64 Q-rows/block, KV tiles of 64.
// T14 async staging with NAMED uint4 scalars (kr0..3/vr0..3) -- rule #20:
// arrays were demoted to scratch last round (WRITE_SIZE 65MB -> 1.45GB).
// Loads for tile kt+1 issue before compute of tile kt; ds_writes land after
// the post-compute barrier -> L2 latency hidden under QK+softmax+PV.
// Q held in registers (pre-scaled by scale*log2e). Defer-max softmax:
// fast path has NO cross-lane reductions; l reduced once in epilogue.
// P written as packed b32 pairs (shfl_xor(1) + cvt_pk) -> bank-conflict free.
// LDS = 45,056 B -> 3 blocks/CU.

#define SEQ 2048
#define DH  128
#define NBH 64          // B*H
#define BM  64          // Q rows per block
#define BN  64          // keys per KV iteration
#define NT  (SEQ / BN)  // 32 KV tiles
#define QK_LD 136       // bf16 elems per row for K tile (128+8): 272B rows
#define VT_LD 72        // (64+8): 144B rows
#define P_LD  72
#define THR 8.0f        // defer-max threshold (exp2 domain): P <= 2^8

typedef __attribute__((ext_vector_type(8))) short short8;
typedef __attribute__((ext_vector_type(4))) float f32x4;

#if __has_builtin(__builtin_amdgcn_exp2f)
#define EXP2F(x) __builtin_amdgcn_exp2f(x)
#else
#define EXP2F(x) exp2f(x)
#endif

// softmax scale folded with log2(e), pre-applied to Q at load time
#define CS (0.08838834764831845f * 1.44269504088896340736f)

__device__ __forceinline__ unsigned int pk_bf16(float lo, float hi) {
    union { __hip_bfloat162 h; unsigned int u; } cv;
    cv.h = __float22bfloat162_rn(make_float2(lo, hi));   // v_cvt_pk_bf16_f32
    return cv.u;
}

// ---- fused prep: V[bh][s][d] f32 -> VT[bh][d][s] bf16 (transpose) and,
// ---- if DOK, K f32 -> bf16 streaming convert (same layout). ----
template<bool DOK>
__global__ __launch_bounds__(256) void prep_kernel(
        const float* __restrict__ v, unsigned short* __restrict__ vt,
        const float* __restrict__ k, unsigned short* __restrict__ kb) {
    __shared__ float tile[64][65];          // +1 pad: transposed reads 2-way free
    const int bh = blockIdx.z;
    const int s0 = blockIdx.x * 64;
    const int d0 = blockIdx.y * 64;
    const int tid = threadIdx.x;

    // --- K convert slice: block-linear id owns 4096 consecutive floats ---
    if (DOK) {
        const size_t kbase = ((size_t)blockIdx.x +
                              32 * ((size_t)blockIdx.y + 2 * (size_t)blockIdx.z)) * 4096;
#pragma unroll
        for (int i = 0; i < 4; ++i) {
            size_t idx = kbase + ((size_t)tid + 256 * i) * 4;
            float4 val = *reinterpret_cast<const float4*>(k + idx);
            uint2 pk;
            pk.x = pk_bf16(val.x, val.y);
            pk.y = pk_bf16(val.z, val.w);
            *reinterpret_cast<uint2*>(kb + idx) = pk;
        }
    }

    // --- V transpose ---
    const float* src = v + ((size_t)bh * SEQ + s0) * DH + d0;
#pragma unroll
    for (int i = 0; i < 4; ++i) {
        int id  = tid + 256 * i;
        int row = id >> 4;                  // 0..63 key
        int c4  = (id & 15) << 2;           // 0..60 d offset
        float4 val = *reinterpret_cast<const float4*>(src + row * DH + c4);
        tile[row][c4 + 0] = val.x;
        tile[row][c4 + 1] = val.y;
        tile[row][c4 + 2] = val.z;
        tile[row][c4 + 3] = val.w;
    }
    __syncthreads();
    unsigned short* dst = vt + ((size_t)bh * DH + d0) * SEQ + s0;
#pragma unroll
    for (int i = 0; i < 2; ++i) {
        int id = tid + 256 * i;
        int dd = id >> 3;                   // 0..63 d row
        int kc = (id & 7) << 3;             // key chunk of 8
        uint4 pk;
        unsigned int* pw = reinterpret_cast<unsigned int*>(&pk);
#pragma unroll
        for (int j = 0; j < 4; ++j)
            pw[j] = pk_bf16(tile[kc + 2 * j][dd], tile[kc + 2 * j + 1][dd]);
        *reinterpret_cast<uint4*>(dst + (size_t)dd * SEQ + kc) = pk;   // 16B coalesced
    }
}

// ---- flash attention ----
template<bool KPRE>
__global__ __launch_bounds__(256, 3) void fattn_kernel(
        const float* __restrict__ q, const float* __restrict__ kf,
        const unsigned short* __restrict__ kb,
        const unsigned short* __restrict__ vt, float* __restrict__ out) {
    __shared__ unsigned short Ks[BN * QK_LD];   // [key][d]
    __shared__ unsigned short Vs[DH * VT_LD];   // [d][key]  (transposed V tile)
    __shared__ unsigned short Ps[BM * P_LD];    // [q_row][key]

    // XCD swizzle: cluster the 32 q-blocks of each bh on one XCD (2048 = 8*256)
    const int wid = ((blockIdx.x & 7) << 8) | (blockIdx.x >> 3);
    const int bh  = wid >> 5;
    const int q0  = (wid & 31) * BM;
    const int tid  = threadIdx.x;
    const int w    = tid >> 6;      // wave 0..3
    const int lane = tid & 63;
    const int l15  = lane & 15;
    const int quad = lane >> 4;

    // ---- Q (16 rows for this wave) into registers, scaled by CS, bf16 ----
    short8 qf[4];
    {
        const float* qptr = q + ((size_t)bh * SEQ + q0 + w * 16 + l15) * DH + quad * 8;
#pragma unroll
        for (int kk = 0; kk < 4; ++kk) {
            float4 x = *reinterpret_cast<const float4*>(qptr + kk * 32);
            float4 y = *reinterpret_cast<const float4*>(qptr + kk * 32 + 4);
            union { short8 s; uint4 u; } cv;
            cv.u.x = pk_bf16(x.x * CS, x.y * CS);
            cv.u.y = pk_bf16(x.z * CS, x.w * CS);
            cv.u.z = pk_bf16(y.x * CS, y.y * CS);
            cv.u.w = pk_bf16(y.z * CS, y.w * CS);
            qf[kk] = cv.s;
        }
    }

    f32x4 o[8];
#pragma unroll
    for (int t = 0; t < 8; ++t) o[t] = (f32x4){0.f, 0.f, 0.f, 0.f};
    float mrow[4] = {-1e30f, -1e30f, -1e30f, -1e30f};
    float lrow[4] = {0.f, 0.f, 0.f, 0.f};   // per-lane PARTIAL sums (reduced in epilogue)

    const float*          kfp  = kf + (size_t)bh * SEQ * DH;
    const unsigned short* kbp  = kb + (size_t)bh * SEQ * DH;
    const unsigned short* vptr = vt + (size_t)bh * DH * SEQ;

    unsigned int* Ps32 = reinterpret_cast<unsigned int*>(Ps);
    const int prow_base = w * 16 + quad * 4;
    // within-row dword offset for packed P writes: evens own t0/t2, odds t1/t3
    const int pdw = (l15 & 1) ? (8 + (l15 >> 1)) : (l15 >> 1);

    // ---- T14 async staging state: NAMED scalars only (no arrays -> no scratch)
    uint4 kr0, kr1, kr2, kr3, vr0, vr1, vr2, vr3;
    const int krow = tid >> 4, kcol = (tid & 15) << 3;   // K stage coords
    const int vrow = tid >> 3, vcol = (tid & 7) << 3;    // V stage coords
    const unsigned short* kst = kbp + (size_t)krow * DH + kcol;
    const unsigned short* vst = vptr + (size_t)vrow * SEQ + vcol;

#define LOAD_TILE(K0)                                                              \
    do {                                                                           \
        const unsigned short* _kp = kst + (size_t)(K0) * DH;                       \
        kr0 = *reinterpret_cast<const uint4*>(_kp);                                \
        kr1 = *reinterpret_cast<const uint4*>(_kp + 16 * DH);                      \
        kr2 = *reinterpret_cast<const uint4*>(_kp + 32 * DH);                      \
        kr3 = *reinterpret_cast<const uint4*>(_kp + 48 * DH);                      \
        const unsigned short* _vp = vst + (K0);                                    \
        vr0 = *reinterpret_cast<const uint4*>(_vp);                                \
        vr1 = *reinterpret_cast<const uint4*>(_vp + 32 * SEQ);                     \
        vr2 = *reinterpret_cast<const uint4*>(_vp + 64 * SEQ);                     \
        vr3 = *reinterpret_cast<const uint4*>(_vp + 96 * SEQ);                     \
    } while (0)

#define WRITE_TILE()                                                               \
    do {                                                                           \
        *reinterpret_cast<uint4*>(&Ks[(krow     ) * QK_LD + kcol]) = kr0;          \
        *reinterpret_cast<uint4*>(&Ks[(krow + 16) * QK_LD + kcol]) = kr1;          \
        *reinterpret_cast<uint4*>(&Ks[(krow + 32) * QK_LD + kcol]) = kr2;          \
        *reinterpret_cast<uint4*>(&Ks[(krow + 48) * QK_LD + kcol]) = kr3;          \
        *reinterpret_cast<uint4*>(&Vs[(vrow     ) * VT_LD + vcol]) = vr0;          \
        *reinterpret_cast<uint4*>(&Vs[(vrow + 32) * VT_LD + vcol]) = vr1;          \
        *reinterpret_cast<uint4*>(&Vs[(vrow + 64) * VT_LD + vcol]) = vr2;          \
        *reinterpret_cast<uint4*>(&Vs[(vrow + 96) * VT_LD + vcol]) = vr3;          \
    } while (0)

    if (KPRE) {
        LOAD_TILE(0);
        WRITE_TILE();
        __syncthreads();
    }

    for (int kt = 0; kt < NT; ++kt) {
        const int k0 = kt * BN;
        if (KPRE) {
            // issue next tile's global loads now; latency hides under compute
            if (kt + 1 < NT) LOAD_TILE(k0 + BN);
        } else {
            // fallback (small ws): synchronous stage, f32 K -> bf16 via cvt_pk
#pragma unroll
            for (int i = 0; i < 8; ++i) {
                int id  = tid + 256 * i;
                int row = id >> 5;
                int c4  = (id & 31) << 2;
                float4 val = *reinterpret_cast<const float4*>(kfp + (size_t)(k0 + row) * DH + c4);
                uint2 pk;
                pk.x = pk_bf16(val.x, val.y);
                pk.y = pk_bf16(val.z, val.w);
                *reinterpret_cast<uint2*>(&Ks[row * QK_LD + c4]) = pk;
            }
#pragma unroll
            for (int i = 0; i < 4; ++i) {
                int id = tid + 256 * i;
                int dd = id >> 3;
                int kc = (id & 7) << 3;
                *reinterpret_cast<uint4*>(&Vs[dd * VT_LD + kc]) =
                    *reinterpret_cast<const uint4*>(vptr + (size_t)dd * SEQ + k0 + kc);
            }
            __syncthreads();
        }

        // ---- S = Q K^T (pre-scaled): wave w computes rows [w*16,w*16+16) x 64 keys
        f32x4 acc[4];
#pragma unroll
        for (int t = 0; t < 4; ++t) acc[t] = (f32x4){0.f, 0.f, 0.f, 0.f};
#pragma unroll
        for (int kk = 0; kk < 4; ++kk) {
            const int koff = kk * 32 + quad * 8;
#pragma unroll
            for (int t = 0; t < 4; ++t) {
                short8 b = *reinterpret_cast<const short8*>(&Ks[(t * 16 + l15) * QK_LD + koff]);
                acc[t] = __builtin_amdgcn_mfma_f32_16x16x32_bf16(qf[kk], b, acc[t], 0, 0, 0);
            }
        }

        // ---- defer-max: fast path needs no cross-lane reduction at all ----
        float lm[4];
#pragma unroll
        for (int r = 0; r < 4; ++r)
            lm[r] = fmaxf(fmaxf(acc[0][r], acc[1][r]), fmaxf(acc[2][r], acc[3][r]));
        float need = fmaxf(fmaxf(lm[0] - mrow[0], lm[1] - mrow[1]),
                           fmaxf(lm[2] - mrow[2], lm[3] - mrow[3]));
        if (__any(need > THR)) {
            // slow path (first tile + rare growth): full row max, rescale o/l
#pragma unroll
            for (int r = 0; r < 4; ++r) {
                float mx = lm[r];
#pragma unroll
                for (int off = 1; off < 16; off <<= 1)
                    mx = fmaxf(mx, __shfl_xor(mx, off));
                float mnew  = fmaxf(mrow[r], mx);
                float alpha = EXP2F(mrow[r] - mnew);
                mrow[r] = mnew;
                lrow[r] *= alpha;
#pragma unroll
                for (int t = 0; t < 8; ++t) o[t][r] *= alpha;
            }
        }

        // ---- P = exp2(S - m) (bounded by 2^8), packed conflict-free writes ----
#pragma unroll
        for (int r = 0; r < 4; ++r) {
            float p0 = EXP2F(acc[0][r] - mrow[r]);
            float p1 = EXP2F(acc[1][r] - mrow[r]);
            float p2 = EXP2F(acc[2][r] - mrow[r]);
            float p3 = EXP2F(acc[3][r] - mrow[r]);
            lrow[r] += (p0 + p1) + (p2 + p3);
            unsigned int a01 = pk_bf16(p0, p1);
            unsigned int a23 = pk_bf16(p2, p3);
            unsigned int s01 = __shfl_xor((int)a01, 1);
            unsigned int s23 = __shfl_xor((int)a23, 1);
            unsigned int w0, w1;
            if (l15 & 1) {  // odd lanes own t1/t3 dwords: low = partner's, high = own
                w0 = (s01 >> 16) | (a01 & 0xffff0000u);
                w1 = (s23 >> 16) | (a23 & 0xffff0000u);
            } else {        // even lanes own t0/t2 dwords: low = own, high = partner's
                w0 = (a01 & 0xffffu) | (s01 << 16);
                w1 = (a23 & 0xffffu) | (s23 << 16);
            }
            const int dw = (prow_base + r) * (P_LD / 2) + pdw;
            Ps32[dw]      = w0;   // cols {t0|t1}
            Ps32[dw + 16] = w1;   // cols {t2|t3}
        }

        // ---- O += P V : A-frag from own P rows, B-frag from VT tile ----
#pragma unroll
        for (int kk = 0; kk < 2; ++kk) {
            const int koff = kk * 32 + quad * 8;
            short8 a = *reinterpret_cast<const short8*>(&Ps[(w * 16 + l15) * P_LD + koff]);
#pragma unroll
            for (int t = 0; t < 8; ++t) {
                short8 b = *reinterpret_cast<const short8*>(&Vs[(t * 16 + l15) * VT_LD + koff]);
                o[t] = __builtin_amdgcn_mfma_f32_16x16x32_bf16(a, b, o[t], 0, 0, 0);
            }
        }
        __syncthreads();   // all waves done reading K/V tiles
        if (KPRE) {
            if (kt + 1 < NT) WRITE_TILE();   // vmcnt drained here, not pre-compute
            __syncthreads();                 // LDS ready for next compute
        }
    }

    // ---- epilogue: reduce distributed l, normalize, store fp32 ----
#pragma unroll
    for (int r = 0; r < 4; ++r) {
#pragma unroll
        for (int off = 1; off < 16; off <<= 1)
            lrow[r] += __shfl_xor(lrow[r], off);
    }
    float* obase = out + ((size_t)bh * SEQ + q0) * DH;
#pragma unroll
    for (int r = 0; r < 4; ++r) {
        float inv = 1.0f / lrow[r];
        int row = w * 16 + quad * 4 + r;
#pragma unroll
        for (int t = 0; t < 8; ++t)
            obase[(size_t)row * DH + t * 16 + l15] = o[t][r] * inv;
    }
}

extern "C" void kernel_launch(void* const* d_in, const int* in_sizes, int n_in,
                              void* d_out, int out_size, void* d_ws, size_t ws_size,
                              hipStream_t stream) {
    const float* q = (const float*)d_in[0];
    const float* k = (const float*)d_in[1];
    const float* v = (const float*)d_in[2];
    float* out = (float*)d_out;
    unsigned short* vt = (unsigned short*)d_ws;                   // 32 MB

    const size_t vt_elems = (size_t)NBH * SEQ * DH;               // 16M shorts
    if (ws_size >= 2 * vt_elems * sizeof(unsigned short)) {
        unsigned short* kbuf = vt + vt_elems;
        prep_kernel<true><<<dim3(SEQ / 64, DH / 64, NBH), dim3(256), 0, stream>>>(v, vt, k, kbuf);
        fattn_kernel<true><<<dim3(SEQ / BM * NBH), dim3(256), 0, stream>>>(q, nullptr, kbuf, vt, out);
    } else {
        prep_kernel<false><<<dim3(SEQ / 64, DH / 64, NBH), dim3(256), 0, stream>>>(v, vt, nullptr, nullptr);
        fattn_kernel<false><<<dim3(SEQ / BM * NBH), dim3(256), 0, stream>>>(q, k, nullptr, vt, out);
    }
}

// Round 5
// 364.390 us; speedup vs baseline: 2.2812x; 1.1523x over previous
//
#include <hip/hip_runtime.h>
#include <hip/hip_bf16.h>

// Attention fwd: B=4 H=16 S=2048 D=128, fp32 in/out, scale = 128^-0.5.
// Prep: V -> VT[bh][d][s] bf16 + K -> bf16 in d_ws (64 MB), 2048 blocks.
// fattn (LDS-bound fix): 32x32x16 MFMA, swapped operands:
//   S^T = K·Q^T  (A = K from LDS, B = Q in regs)  -> softmax per-lane scalar
//   O^T = V^T·P^T (A = V from LDS, B = P repacked in regs via cvt_pk+shfl)
// -> LDS bytes/FLOP halved vs 16x16, P LDS round-trip eliminated.
// BM=128 (4 waves x 32 q-rows), BN=64. LDS = 35,840 B. Defer-max softmax,
// T14 named-scalar staging (issued between softmax and PV), XCD swizzle.

#define SEQ 2048
#define DH  128
#define NBH 64          // B*H
#define BM  128         // Q rows per block (32 per wave)
#define BN  64          // keys per KV iteration
#define NT  (SEQ / BN)  // 32 KV tiles
#define QK_LD 136       // bf16 elems per row for K tile (128+8): 272B rows
#define VT_LD 72        // (64+8): 144B rows
#define P_LD  72        // fallback kernel only
#define THR 8.0f        // defer-max threshold (exp2 domain): P <= 2^8

typedef __attribute__((ext_vector_type(8))) short short8;
typedef __attribute__((ext_vector_type(4))) float f32x4;
typedef __attribute__((ext_vector_type(16))) float f32x16;

#if __has_builtin(__builtin_amdgcn_exp2f)
#define EXP2F(x) __builtin_amdgcn_exp2f(x)
#else
#define EXP2F(x) exp2f(x)
#endif

// softmax scale folded with log2(e), pre-applied to Q at load time
#define CS (0.08838834764831845f * 1.44269504088896340736f)

__device__ __forceinline__ unsigned int pk_bf16(float lo, float hi) {
    union { __hip_bfloat162 h; unsigned int u; } cv;
    cv.h = __float22bfloat162_rn(make_float2(lo, hi));   // v_cvt_pk_bf16_f32
    return cv.u;
}

// ---- fused prep: V[bh][s][d] f32 -> VT[bh][d][s] bf16 (transpose, full-D
// ---- 64x128 tile per block) and, if DOK, K f32 -> bf16 streaming. ----
template<bool DOK>
__global__ __launch_bounds__(256) void prep_kernel(
        const float* __restrict__ v, unsigned short* __restrict__ vt,
        const float* __restrict__ k, unsigned short* __restrict__ kb) {
    __shared__ float tile[64][129];         // [key][d], +1 pad
    const int bh  = blockIdx.z;
    const int s0  = blockIdx.x * 64;
    const int tid = threadIdx.x;

    if (DOK) {
        const size_t kbase = ((size_t)blockIdx.x + 32 * (size_t)bh) * 8192;
#pragma unroll
        for (int i = 0; i < 8; ++i) {
            size_t idx = kbase + ((size_t)tid + 256 * i) * 4;
            float4 val = *reinterpret_cast<const float4*>(k + idx);
            uint2 pk;
            pk.x = pk_bf16(val.x, val.y);
            pk.y = pk_bf16(val.z, val.w);
            *reinterpret_cast<uint2*>(kb + idx) = pk;
        }
    }

    const float* src = v + ((size_t)bh * SEQ + s0) * DH;
#pragma unroll
    for (int i = 0; i < 8; ++i) {
        int id  = tid + 256 * i;
        int row = id >> 5;                  // 0..63 key
        int c4  = (id & 31) << 2;           // 0..124 d
        float4 val = *reinterpret_cast<const float4*>(src + row * DH + c4);
        tile[row][c4 + 0] = val.x;
        tile[row][c4 + 1] = val.y;
        tile[row][c4 + 2] = val.z;
        tile[row][c4 + 3] = val.w;
    }
    __syncthreads();
    unsigned short* dst = vt + (size_t)bh * DH * SEQ + s0;
#pragma unroll
    for (int i = 0; i < 4; ++i) {
        int id = tid + 256 * i;
        int dd = id >> 3;                   // 0..127 d row
        int kc = (id & 7) << 3;             // key chunk of 8
        uint4 pk;
        unsigned int* pw = reinterpret_cast<unsigned int*>(&pk);
#pragma unroll
        for (int j = 0; j < 4; ++j)
            pw[j] = pk_bf16(tile[kc + 2 * j][dd], tile[kc + 2 * j + 1][dd]);
        *reinterpret_cast<uint4*>(dst + (size_t)dd * SEQ + kc) = pk;
    }
}

// ---- flash attention, 32x32x16 swapped-operand structure ----
__global__ __launch_bounds__(256, 2) void fattn_kernel(
        const float* __restrict__ q, const unsigned short* __restrict__ kb,
        const unsigned short* __restrict__ vt, float* __restrict__ out) {
    __shared__ unsigned short Ks[BN * QK_LD];   // [key][d]
    __shared__ unsigned short Vs[DH * VT_LD];   // [d][key]

    // XCD swizzle: 1024 blocks = 8 XCDs x 128; 16 q-blocks per bh contiguous
    const int wid = ((blockIdx.x & 7) << 7) | (blockIdx.x >> 3);
    const int bh  = wid >> 4;
    const int q0  = (wid & 15) * BM;
    const int tid  = threadIdx.x;
    const int w    = tid >> 6;      // wave 0..3 -> q-rows [32w, 32w+32)
    const int lane = tid & 63;
    const int l31  = lane & 31;
    const int hi   = lane >> 5;

    // ---- Q (one row per lane: q0 + 32w + l31) into regs as B-frags ----
    short8 qb[8];
    {
        const float* qptr = q + ((size_t)bh * SEQ + q0 + w * 32 + l31) * DH + hi * 8;
#pragma unroll
        for (int ks = 0; ks < 8; ++ks) {
            float4 x = *reinterpret_cast<const float4*>(qptr + 16 * ks);
            float4 y = *reinterpret_cast<const float4*>(qptr + 16 * ks + 4);
            union { short8 s; uint4 u; } cv;
            cv.u.x = pk_bf16(x.x * CS, x.y * CS);
            cv.u.y = pk_bf16(x.z * CS, x.w * CS);
            cv.u.z = pk_bf16(y.x * CS, y.y * CS);
            cv.u.w = pk_bf16(y.z * CS, y.w * CS);
            qb[ks] = cv.s;
        }
    }

    f32x16 o0, o1, o2, o3;                  // O^T[d=32c+..][qrow=l31]
#pragma unroll
    for (int i = 0; i < 16; ++i) { o0[i] = 0.f; o1[i] = 0.f; o2[i] = 0.f; o3[i] = 0.f; }
    float m = -1e30f, lsum = 0.f;           // per-lane (qrow) stats; pair l<->l^32

    const unsigned short* kbp  = kb + (size_t)bh * SEQ * DH;
    const unsigned short* vptr = vt + (size_t)bh * DH * SEQ;

    // ---- T14 staging: NAMED scalars only (rule #20) ----
    uint4 kr0, kr1, kr2, kr3, vr0, vr1, vr2, vr3;
    const int krow = tid >> 4, kcol = (tid & 15) << 3;
    const int vrow = tid >> 3, vcol = (tid & 7) << 3;
    const unsigned short* kst = kbp + (size_t)krow * DH + kcol;
    const unsigned short* vst = vptr + (size_t)vrow * SEQ + vcol;

#define LOAD_TILE(K0)                                                              \
    do {                                                                           \
        const unsigned short* _kp = kst + (size_t)(K0) * DH;                       \
        kr0 = *reinterpret_cast<const uint4*>(_kp);                                \
        kr1 = *reinterpret_cast<const uint4*>(_kp + 16 * DH);                      \
        kr2 = *reinterpret_cast<const uint4*>(_kp + 32 * DH);                      \
        kr3 = *reinterpret_cast<const uint4*>(_kp + 48 * DH);                      \
        const unsigned short* _vp = vst + (K0);                                    \
        vr0 = *reinterpret_cast<const uint4*>(_vp);                                \
        vr1 = *reinterpret_cast<const uint4*>(_vp + 32 * SEQ);                     \
        vr2 = *reinterpret_cast<const uint4*>(_vp + 64 * SEQ);                     \
        vr3 = *reinterpret_cast<const uint4*>(_vp + 96 * SEQ);                     \
    } while (0)

#define WRITE_TILE()                                                               \
    do {                                                                           \
        *reinterpret_cast<uint4*>(&Ks[(krow     ) * QK_LD + kcol]) = kr0;          \
        *reinterpret_cast<uint4*>(&Ks[(krow + 16) * QK_LD + kcol]) = kr1;          \
        *reinterpret_cast<uint4*>(&Ks[(krow + 32) * QK_LD + kcol]) = kr2;          \
        *reinterpret_cast<uint4*>(&Ks[(krow + 48) * QK_LD + kcol]) = kr3;          \
        *reinterpret_cast<uint4*>(&Vs[(vrow     ) * VT_LD + vcol]) = vr0;          \
        *reinterpret_cast<uint4*>(&Vs[(vrow + 32) * VT_LD + vcol]) = vr1;          \
        *reinterpret_cast<uint4*>(&Vs[(vrow + 64) * VT_LD + vcol]) = vr2;          \
        *reinterpret_cast<uint4*>(&Vs[(vrow + 96) * VT_LD + vcol]) = vr3;          \
    } while (0)

    LOAD_TILE(0);
    WRITE_TILE();
    __syncthreads();

    // LDS read bases: A-frag layout lane l -> row l&31, k-elems (l>>5)*8+0..7
    const unsigned short* KsA = &Ks[l31 * QK_LD + hi * 8];
    const unsigned short* VsA = &Vs[l31 * VT_LD + hi * 8];

    for (int kt = 0; kt < NT; ++kt) {
        // ---- S^T = K . Q^T : s0 = keys[0,32), s1 = keys[32,64) ----
        f32x16 s0, s1;
#pragma unroll
        for (int i = 0; i < 16; ++i) { s0[i] = 0.f; s1[i] = 0.f; }
        __builtin_amdgcn_s_setprio(1);
#pragma unroll
        for (int ks = 0; ks < 8; ++ks) {
            short8 a0 = *reinterpret_cast<const short8*>(KsA + 16 * ks);
            short8 a1 = *reinterpret_cast<const short8*>(KsA + 32 * QK_LD + 16 * ks);
            s0 = __builtin_amdgcn_mfma_f32_32x32x16_bf16(a0, qb[ks], s0, 0, 0, 0);
            s1 = __builtin_amdgcn_mfma_f32_32x32x16_bf16(a1, qb[ks], s1, 0, 0, 0);
        }
        __builtin_amdgcn_s_setprio(0);

        // ---- per-lane softmax (row = own qrow; keys split lane<->lane^32) ----
        float mx = s0[0];
#pragma unroll
        for (int i = 1; i < 16; ++i) mx = fmaxf(mx, s0[i]);
#pragma unroll
        for (int i = 0; i < 16; ++i) mx = fmaxf(mx, s1[i]);
        mx = fmaxf(mx, __shfl_xor(mx, 32));     // pair-consistent row max
        if (__any(mx - m > THR)) {
            float mn = fmaxf(m, mx);
            float al = EXP2F(m - mn);
            m = mn; lsum *= al;
#pragma unroll
            for (int i = 0; i < 16; ++i) { o0[i] *= al; o1[i] *= al; o2[i] *= al; o3[i] *= al; }
        }
#pragma unroll
        for (int i = 0; i < 16; ++i) s0[i] = EXP2F(s0[i] - m);
#pragma unroll
        for (int i = 0; i < 16; ++i) s1[i] = EXP2F(s1[i] - m);
        float ls = 0.f;
#pragma unroll
        for (int i = 0; i < 16; ++i) ls += s0[i] + s1[i];
        lsum += ls;

        // ---- repack P -> PV B-frags (P^T lane layout), cvt_pk + shfl_xor(32)
        // C-layout key of reg r in group g: 32g + (r&3) + 8*(r>>2) + 4*hi
        short8 pf0, pf1, pf2, pf3;
#define MAKE_PF(PF, SG, S)                                                         \
        {                                                                          \
            unsigned pq0 = pk_bf16(SG[8*(S)+0], SG[8*(S)+1]);                      \
            unsigned pq1 = pk_bf16(SG[8*(S)+2], SG[8*(S)+3]);                      \
            unsigned pq2 = pk_bf16(SG[8*(S)+4], SG[8*(S)+5]);                      \
            unsigned pq3 = pk_bf16(SG[8*(S)+6], SG[8*(S)+7]);                      \
            unsigned px0 = (unsigned)__shfl_xor((int)pq0, 32);                     \
            unsigned px1 = (unsigned)__shfl_xor((int)pq1, 32);                     \
            unsigned px2 = (unsigned)__shfl_xor((int)pq2, 32);                     \
            unsigned px3 = (unsigned)__shfl_xor((int)pq3, 32);                     \
            union { short8 s; uint4 u; } cv;                                       \
            cv.u.x = hi ? px2 : pq0;                                               \
            cv.u.y = hi ? px3 : pq1;                                               \
            cv.u.z = hi ? pq2 : px0;                                               \
            cv.u.w = hi ? pq3 : px1;                                               \
            PF = cv.s;                                                             \
        }
        MAKE_PF(pf0, s0, 0)    // keys  0..15
        MAKE_PF(pf1, s0, 1)    // keys 16..31
        MAKE_PF(pf2, s1, 0)    // keys 32..47
        MAKE_PF(pf3, s1, 1)    // keys 48..63

        // issue next tile's global loads: latency hides under PV + barrier
        if (kt + 1 < NT) LOAD_TILE((kt + 1) * BN);

        // ---- O^T += V^T . P^T ----
        __builtin_amdgcn_s_setprio(1);
#define PV_C(OC, C)                                                                \
        {                                                                          \
            short8 va0 = *reinterpret_cast<const short8*>(VsA + (32*(C)) * VT_LD);      \
            short8 va1 = *reinterpret_cast<const short8*>(VsA + (32*(C)) * VT_LD + 16); \
            short8 va2 = *reinterpret_cast<const short8*>(VsA + (32*(C)) * VT_LD + 32); \
            short8 va3 = *reinterpret_cast<const short8*>(VsA + (32*(C)) * VT_LD + 48); \
            OC = __builtin_amdgcn_mfma_f32_32x32x16_bf16(va0, pf0, OC, 0, 0, 0);   \
            OC = __builtin_amdgcn_mfma_f32_32x32x16_bf16(va1, pf1, OC, 0, 0, 0);   \
            OC = __builtin_amdgcn_mfma_f32_32x32x16_bf16(va2, pf2, OC, 0, 0, 0);   \
            OC = __builtin_amdgcn_mfma_f32_32x32x16_bf16(va3, pf3, OC, 0, 0, 0);   \
        }
        PV_C(o0, 0) PV_C(o1, 1) PV_C(o2, 2) PV_C(o3, 3)
        __builtin_amdgcn_s_setprio(0);

        __syncthreads();                    // all waves done reading K/V
        if (kt + 1 < NT) WRITE_TILE();      // vmcnt drained here
        __syncthreads();                    // LDS ready for next compute
    }

    // ---- epilogue: pair-reduce l, normalize, store fp32 ----
    lsum += __shfl_xor(lsum, 32);
    float inv = 1.0f / lsum;
    float* obase = out + ((size_t)bh * SEQ + q0 + w * 32 + l31) * DH + 4 * hi;
#define STORE_C(OC, C)                                                             \
    {                                                                              \
        _Pragma("unroll")                                                          \
        for (int u = 0; u < 4; ++u) {                                              \
            float4 st;                                                             \
            st.x = OC[4*u+0] * inv; st.y = OC[4*u+1] * inv;                        \
            st.z = OC[4*u+2] * inv; st.w = OC[4*u+3] * inv;                        \
            *reinterpret_cast<float4*>(obase + 32*(C) + 8*u) = st;                 \
        }                                                                          \
    }
    STORE_C(o0, 0) STORE_C(o1, 1) STORE_C(o2, 2) STORE_C(o3, 3)
}

// ---- fallback (ws < 64 MB): round-2-verified 16x16 kernel, in-loop K cvt ----
__global__ __launch_bounds__(256, 3) void fattn_fallback(
        const float* __restrict__ q, const float* __restrict__ kf,
        const unsigned short* __restrict__ vt, float* __restrict__ out) {
    __shared__ unsigned short Ks[64 * QK_LD];
    __shared__ unsigned short Vs[DH * VT_LD];
    __shared__ unsigned short Ps[64 * P_LD];

    const int wid = ((blockIdx.x & 7) << 8) | (blockIdx.x >> 3);
    const int bh  = wid >> 5;
    const int q0  = (wid & 31) * 64;
    const int tid  = threadIdx.x;
    const int w    = tid >> 6;
    const int lane = tid & 63;
    const int l15  = lane & 15;
    const int quad = lane >> 4;

    short8 qf[4];
    {
        const float* qptr = q + ((size_t)bh * SEQ + q0 + w * 16 + l15) * DH + quad * 8;
#pragma unroll
        for (int kk = 0; kk < 4; ++kk) {
            float4 x = *reinterpret_cast<const float4*>(qptr + kk * 32);
            float4 y = *reinterpret_cast<const float4*>(qptr + kk * 32 + 4);
            union { short8 s; uint4 u; } cv;
            cv.u.x = pk_bf16(x.x * CS, x.y * CS);
            cv.u.y = pk_bf16(x.z * CS, x.w * CS);
            cv.u.z = pk_bf16(y.x * CS, y.y * CS);
            cv.u.w = pk_bf16(y.z * CS, y.w * CS);
            qf[kk] = cv.s;
        }
    }

    f32x4 o[8];
#pragma unroll
    for (int t = 0; t < 8; ++t) o[t] = (f32x4){0.f, 0.f, 0.f, 0.f};
    float mrow[4] = {-1e30f, -1e30f, -1e30f, -1e30f};
    float lrow[4] = {0.f, 0.f, 0.f, 0.f};

    const float*          kfp  = kf + (size_t)bh * SEQ * DH;
    const unsigned short* vptr = vt + (size_t)bh * DH * SEQ;

    unsigned int* Ps32 = reinterpret_cast<unsigned int*>(Ps);
    const int prow_base = w * 16 + quad * 4;
    const int pdw = (l15 & 1) ? (8 + (l15 >> 1)) : (l15 >> 1);

    for (int kt = 0; kt < NT; ++kt) {
        const int k0 = kt * BN;
#pragma unroll
        for (int i = 0; i < 8; ++i) {
            int id  = tid + 256 * i;
            int row = id >> 5;
            int c4  = (id & 31) << 2;
            float4 val = *reinterpret_cast<const float4*>(kfp + (size_t)(k0 + row) * DH + c4);
            uint2 pk;
            pk.x = pk_bf16(val.x, val.y);
            pk.y = pk_bf16(val.z, val.w);
            *reinterpret_cast<uint2*>(&Ks[row * QK_LD + c4]) = pk;
        }
#pragma unroll
        for (int i = 0; i < 4; ++i) {
            int id = tid + 256 * i;
            int dd = id >> 3;
            int kc = (id & 7) << 3;
            *reinterpret_cast<uint4*>(&Vs[dd * VT_LD + kc]) =
                *reinterpret_cast<const uint4*>(vptr + (size_t)dd * SEQ + k0 + kc);
        }
        __syncthreads();

        f32x4 acc[4];
#pragma unroll
        for (int t = 0; t < 4; ++t) acc[t] = (f32x4){0.f, 0.f, 0.f, 0.f};
#pragma unroll
        for (int kk = 0; kk < 4; ++kk) {
            const int koff = kk * 32 + quad * 8;
#pragma unroll
            for (int t = 0; t < 4; ++t) {
                short8 b = *reinterpret_cast<const short8*>(&Ks[(t * 16 + l15) * QK_LD + koff]);
                acc[t] = __builtin_amdgcn_mfma_f32_16x16x32_bf16(qf[kk], b, acc[t], 0, 0, 0);
            }
        }

        float lm[4];
#pragma unroll
        for (int r = 0; r < 4; ++r)
            lm[r] = fmaxf(fmaxf(acc[0][r], acc[1][r]), fmaxf(acc[2][r], acc[3][r]));
        float need = fmaxf(fmaxf(lm[0] - mrow[0], lm[1] - mrow[1]),
                           fmaxf(lm[2] - mrow[2], lm[3] - mrow[3]));
        if (__any(need > THR)) {
#pragma unroll
            for (int r = 0; r < 4; ++r) {
                float mx = lm[r];
#pragma unroll
                for (int off = 1; off < 16; off <<= 1)
                    mx = fmaxf(mx, __shfl_xor(mx, off));
                float mnew  = fmaxf(mrow[r], mx);
                float alpha = EXP2F(mrow[r] - mnew);
                mrow[r] = mnew;
                lrow[r] *= alpha;
#pragma unroll
                for (int t = 0; t < 8; ++t) o[t][r] *= alpha;
            }
        }

#pragma unroll
        for (int r = 0; r < 4; ++r) {
            float p0 = EXP2F(acc[0][r] - mrow[r]);
            float p1 = EXP2F(acc[1][r] - mrow[r]);
            float p2 = EXP2F(acc[2][r] - mrow[r]);
            float p3 = EXP2F(acc[3][r] - mrow[r]);
            lrow[r] += (p0 + p1) + (p2 + p3);
            unsigned int a01 = pk_bf16(p0, p1);
            unsigned int a23 = pk_bf16(p2, p3);
            unsigned int s01 = __shfl_xor((int)a01, 1);
            unsigned int s23 = __shfl_xor((int)a23, 1);
            unsigned int w0, w1;
            if (l15 & 1) {
                w0 = (s01 >> 16) | (a01 & 0xffff0000u);
                w1 = (s23 >> 16) | (a23 & 0xffff0000u);
            } else {
                w0 = (a01 & 0xffffu) | (s01 << 16);
                w1 = (a23 & 0xffffu) | (s23 << 16);
            }
            const int dw = (prow_base + r) * (P_LD / 2) + pdw;
            Ps32[dw]      = w0;
            Ps32[dw + 16] = w1;
        }

#pragma unroll
        for (int kk = 0; kk < 2; ++kk) {
            const int koff = kk * 32 + quad * 8;
            short8 a = *reinterpret_cast<const short8*>(&Ps[(w * 16 + l15) * P_LD + koff]);
#pragma unroll
            for (int t = 0; t < 8; ++t) {
                short8 b = *reinterpret_cast<const short8*>(&Vs[(t * 16 + l15) * VT_LD + koff]);
                o[t] = __builtin_amdgcn_mfma_f32_16x16x32_bf16(a, b, o[t], 0, 0, 0);
            }
        }
        __syncthreads();
    }

#pragma unroll
    for (int r = 0; r < 4; ++r) {
#pragma unroll
        for (int off = 1; off < 16; off <<= 1)
            lrow[r] += __shfl_xor(lrow[r], off);
    }
    float* obase = out + ((size_t)bh * SEQ + q0) * DH;
#pragma unroll
    for (int r = 0; r < 4; ++r) {
        float inv = 1.0f / lrow[r];
        int row = w * 16 + quad * 4 + r;
#pragma unroll
        for (int t = 0; t < 8; ++t)
            obase[(size_t)row * DH + t * 16 + l15] = o[t][r] * inv;
    }
}

extern "C" void kernel_launch(void* const* d_in, const int* in_sizes, int n_in,
                              void* d_out, int out_size, void* d_ws, size_t ws_size,
                              hipStream_t stream) {
    const float* q = (const float*)d_in[0];
    const float* k = (const float*)d_in[1];
    const float* v = (const float*)d_in[2];
    float* out = (float*)d_out;
    unsigned short* vt = (unsigned short*)d_ws;                   // 32 MB

    const size_t vt_elems = (size_t)NBH * SEQ * DH;               // 16M shorts
    if (ws_size >= 2 * vt_elems * sizeof(unsigned short)) {
        unsigned short* kbuf = vt + vt_elems;
        prep_kernel<true><<<dim3(SEQ / 64, 1, NBH), dim3(256), 0, stream>>>(v, vt, k, kbuf);
        fattn_kernel<<<dim3((SEQ / BM) * NBH), dim3(256), 0, stream>>>(q, kbuf, vt, out);
    } else {
        prep_kernel<false><<<dim3(SEQ / 64, 1, NBH), dim3(256), 0, stream>>>(v, vt, nullptr, nullptr);
        fattn_fallback<<<dim3((SEQ / 64) * NBH), dim3(256), 0, stream>>>(q, k, vt, out);
    }
}